// Round 10
// baseline (117.167 us; speedup 1.0000x reference)
//
#include <hip/hip_runtime.h>
#include <hip/hip_bf16.h>
#include <cstdint>
#include <cstddef>

// IR-Net binary conv 3x3 s1 p1 + BN(inference) + hardtanh, B=32 Cin=Cout=256 H=W=56.
// Ternary operands -> EXACT int8 MFMA implicit GEMM (mfma_i32_16x16x64_i8).
// R10 = R9 with register economics fixed:
//   - af prefetch 1-deep ping-pong (af[2][8], 64 VGPR) pinned at TOP of each
//     unrolled step via sched_barrier(0) (distance ~1 full step >= L2 latency;
//     R8 proved unpinned collapses to 0-distance, R9 proved the pin works)
//   - __launch_bounds__(256,1): lift the 128-VGPR cliff that made R9 spill
//     (WRITE 126MB sentinel); LDS 64KB still fixes occupancy at 2 blocks/CU.

typedef int int4v __attribute__((ext_vector_type(4)));

#define CIN   256
#define COUT  256
#define SPAT  3136   // 56*56
#define SPAD  3364   // 58*58 padded spatial
#define BATCH 32
#define XHALF 32768  // 256 rows x 128 B

// ---------------- weight prep: standardize, sign, scatter to A-fragment order ----------------
__device__ inline float block_reduce(float v, float* red, int t) {
  red[t] = v; __syncthreads();
#pragma unroll
  for (int o = 128; o > 0; o >>= 1) {
    if (t < o) red[t] += red[t + o];
    __syncthreads();
  }
  float r = red[0];
  __syncthreads();
  return r;
}

__global__ __launch_bounds__(256) void prep_w_kernel(
    const float* __restrict__ wgt, const float* __restrict__ gamma,
    const float* __restrict__ beta, const float* __restrict__ rmean,
    const float* __restrict__ rvar, int8_t* __restrict__ wfrag,
    float* __restrict__ Sc, float* __restrict__ Tc) {
  const int co = blockIdx.x;
  const int t  = threadIdx.x;
  __shared__ float red[256];
  const float* wc = wgt + (size_t)co * 2304;
  float v[9];
#pragma unroll
  for (int j = 0; j < 9; ++j) v[j] = wc[t + j * 256];
  float s = 0.f;
#pragma unroll
  for (int j = 0; j < 9; ++j) s += v[j];
  const float total = block_reduce(s, red, t);
  const float mean = total * (1.0f / 2304.0f);
  float ss = 0.f, sa = 0.f;
#pragma unroll
  for (int j = 0; j < 9; ++j) {
    float d = v[j] - mean;
    ss += d * d;
    sa += fabsf(d);
  }
  const float var_sum = block_reduce(ss, red, t);
  const float abs_sum = block_reduce(sa, red, t);
  const float stdv = sqrtf(var_sum / 2303.0f);       // unbiased (ddof=1)
  const float mean_abs = abs_sum / (2304.0f * stdv); // mean |bw|
  const float sw = exp2f(rintf(log2f(mean_abs)));    // half-even like jnp.round

  const int z = co >> 7, row = co & 127;
  const int wv = row >> 6, m = (row >> 4) & 3, l15w = row & 15;
#pragma unroll
  for (int j = 0; j < 9; ++j) {
    int i = t + j * 256;          // i = cin*9 + tap  (OIHW flat)
    int cin = i / 9;
    int tap = i - cin * 9;
    float d = v[j] - mean;
    int8_t bits = (d > 0.f) ? (int8_t)1 : ((d < 0.f) ? (int8_t)-1 : (int8_t)0);
    // A-fragment order: [z][g=c0i*9+tap][wv][m*2+kb][lane(64)][e(16)]
    int c0i = cin >> 7, cl = cin & 127;
    int chunk = cl >> 4;                 // 0..7 (16 cin each)
    int kb = chunk >> 2, chp = chunk & 3, e = cl & 15;
    int lane = chp * 16 + l15w;
    int g = c0i * 9 + tap;
    size_t flat = (size_t)z * 294912 + (size_t)(g * 2 + wv) * 8192
                + (m * 2 + kb) * 1024 + lane * 16 + e;
    wfrag[flat] = bits;
  }
  if (t == 0) {
    float inv = gamma[co] / sqrtf(rvar[co] + 1e-5f);
    Sc[co] = sw * inv;
    Tc[co] = beta[co] - rmean[co] * inv;
  }
}

// ---------------- activation pack (+halo clear): sign(x) -> i8, padded [b][58*58][cin] ----------------
__global__ __launch_bounds__(256) void pack_x_kernel(const float* __restrict__ x,
                                                     int8_t* __restrict__ xp) {
  const int b   = blockIdx.y;
  const int tid = threadIdx.x;
  if (blockIdx.x == 49) {                // halo block: zero the 228 pad pixels
    int8_t* xpb = xp + (size_t)b * SPAD * CIN;
    const int4v z = (int4v){0, 0, 0, 0};
    for (int q = tid; q < 228 * 16; q += 256) {
      int p = q >> 4, c = q & 15;
      int pp;
      if (p < 58)       pp = p;                      // top row 0
      else if (p < 116) pp = 57 * 58 + (p - 58);     // bottom row 57
      else if (p < 172) pp = (p - 116 + 1) * 58;     // left col, rows 1..56
      else              pp = (p - 172 + 1) * 58 + 57;// right col, rows 1..56
      *(int4v*)(xpb + (size_t)pp * CIN + c * 16) = z;
    }
    return;
  }
  const int s0  = blockIdx.x * 64;
  __shared__ uint8_t xt[64][272];        // 64 px x 256 cin bytes (+16 pad)
  const int g  = tid >> 6;               // cin quarter 0..3
  const int si = tid & 63;               // px within chunk
#pragma unroll
  for (int k = 0; k < 4; ++k) {          // 16 cin per iter -> one 16B LDS store
    const int cin16 = (g * 4 + k) * 16;
    const float* src = x + ((size_t)b * CIN + cin16) * SPAT + s0 + si;
    uint32_t w[4] = {0u, 0u, 0u, 0u};
#pragma unroll
    for (int e = 0; e < 16; ++e) {
      float v = src[(size_t)e * SPAT];
      uint32_t sb = (v > 0.f) ? 1u : ((v < 0.f) ? 0xFFu : 0u);
      w[e >> 2] |= sb << ((e & 3) * 8);
    }
    *(int4v*)&xt[si][cin16] = (int4v){(int)w[0], (int)w[1], (int)w[2], (int)w[3]};
  }
  __syncthreads();
  const int row = tid >> 2;              // px 0..63
  const int sub = tid & 3;               // 64-cin quarter
  const int s = s0 + row;
  const int h = s / 56;
  int8_t* dst = xp + ((size_t)b * SPAD + (size_t)(s + 2 * h + 59)) * CIN + sub * 64;
#pragma unroll
  for (int j = 0; j < 4; ++j)
    *(int4v*)(dst + j * 16) = *(const int4v*)&xt[row][sub * 64 + j * 16];
}

// ---------------- async global->LDS, 16B ----------------
__device__ __forceinline__ void gload_lds16(const void* g, void* l) {
  __builtin_amdgcn_global_load_lds(
      (const __attribute__((address_space(1))) uint32_t*)g,
      (__attribute__((address_space(3))) uint32_t*)l, 16, 0, 0);
}

// ---------------- binary conv as implicit GEMM (i8 MFMA) ----------------
// Block: 128co x 128px, one image; 4 waves, wave = 64co x 64px, acc[4][4] i32.
// 18 steps (2 cin-halves x 9 taps), fully unrolled; barrier only at prologue +
// half boundary. W: global->reg 1-deep pinned prefetch. X: both halves in LDS.
__global__ __launch_bounds__(256, 1) void conv_kernel(
    const int8_t* __restrict__ xp, const int8_t* __restrict__ wfrag,
    const float* __restrict__ Sc, const float* __restrict__ Tc,
    float* __restrict__ out) {
  const int tile = blockIdx.x;           // 0..24
  const int b    = blockIdx.y;           // 0..31
  const int z    = blockIdx.z;           // co half
  const int co0  = z * 128;
  const int s0   = tile * 128;

  const int tid  = threadIdx.x;
  const int lane = tid & 63;
  const int wave = tid >> 6;
  const int wv   = wave >> 1;            // co 64-half within block
  const int wco  = wv * 64;
  const int wp   = (wave & 1) * 64;      // px 64-half
  const int l15  = lane & 15;
  const int chp  = lane >> 4;            // 16B k-chunk position 0..3

  __shared__ uint8_t XsF[2 * XHALF];     // 64 KB: two cin-halves, 128B rows, swizzled

  const int h0   = s0 / 56;
  const int base = s0 + 2 * h0;          // padded(s)=s+2h+59; base = padded(s0)-59

  // per-lane row offsets rel. to base (r = offn + tapoff in [0,249])
  int offn[4];
#pragma unroll
  for (int n = 0; n < 4; ++n) {
    int s = s0 + wp + n * 16 + l15;
    int sc = s < SPAT ? s : SPAT - 1;    // dummy px clamped (stores masked)
    int h = sc / 56;
    offn[n] = sc + 2 * h + 59 - base;    // in [59, 190]
  }

  const int8_t* xb  = xp + (size_t)b * SPAD * CIN;
  const int8_t* wba = wfrag + (size_t)z * 294912 + (size_t)wv * 8192 + lane * 16;

  // stage one cin-half: 2048 16B chunks (256 rows x 8), source pre-swizzled
  auto issueX = [&](int bufi, int c0e) {
#pragma unroll
    for (int j = 0; j < 8; ++j) {
      int q   = j * 256 + tid;
      int row = q >> 3, c = q & 7;
      int gr  = base + row;
      if (gr > SPAD - 1) gr = SPAD - 1;  // clamp: only feeds dummy px
      gload_lds16(xb + (size_t)gr * CIN + c0e + ((c ^ (row & 7)) << 4),
                  XsF + bufi * XHALF + (q << 4));
    }
  };

  int4v af[2][8];                        // ping-pong 1-deep prefetch (64 VGPR)
  auto loadAf = [&](int g, int buf) {
#pragma unroll
    for (int q8 = 0; q8 < 8; ++q8)
      af[buf][q8] = *(const int4v*)(wba + (size_t)g * 16384 + q8 * 1024);
  };

  int4v acc[4][4];
#pragma unroll
  for (int m = 0; m < 4; ++m)
#pragma unroll
    for (int n = 0; n < 4; ++n) acc[m][n] = (int4v){0, 0, 0, 0};

  // prologue: X0 (16 vmem), af0 (8), X1 (16); pin order, wait own X0 only
  issueX(0, 0);
  loadAf(0, 0);
  issueX(1, 128);
  __builtin_amdgcn_sched_barrier(0);
  asm volatile("s_waitcnt vmcnt(24)" ::: "memory");  // X0 retired (af0 + X1 fly)
  __builtin_amdgcn_s_barrier();          // all waves' X0 visible

#pragma unroll
  for (int s = 0; s < 18; ++s) {
    const int cur = s & 1;
    const int tap = s < 9 ? s : s - 9;
    const int tapoff = (tap / 3) * 58 + (tap - (tap / 3) * 3) - 59;
    const int hof = (s >= 9) ? XHALF : 0;

    if (s == 9) {                        // all waves' X1 long retired (FIFO)
      __builtin_amdgcn_s_barrier();
    }

    // pinned 1-deep W prefetch at TOP of step: distance to use = 1 full step
    if (s < 17) {
      loadAf(s + 1, cur ^ 1);
      __builtin_amdgcn_sched_barrier(0); // issues stay here, can't sink to use
    }

    // bf reads: XOR-swizzled chunk within 128B row
    int4v bf[8];
#pragma unroll
    for (int kb = 0; kb < 2; ++kb)
#pragma unroll
      for (int n = 0; n < 4; ++n) {
        int r = offn[n] + tapoff;
        bf[kb * 4 + n] = *(const int4v*)(XsF + hof + (r << 7)
                                         + (((kb * 4 + chp) ^ (r & 7)) << 4));
      }

    __builtin_amdgcn_s_setprio(1);
#pragma unroll
    for (int kb = 0; kb < 2; ++kb)
#pragma unroll
      for (int m = 0; m < 4; ++m)
#pragma unroll
        for (int n = 0; n < 4; ++n)
          acc[m][n] = __builtin_amdgcn_mfma_i32_16x16x64_i8(
              af[cur][m * 2 + kb], bf[kb * 4 + n], acc[m][n], 0, 0, 0);
    __builtin_amdgcn_s_setprio(0);
  }

  // epilogue: out = clip((float)acc * S + T), layout [b][co][s]
#pragma unroll
  for (int m = 0; m < 4; ++m) {
    const int cor0 = co0 + wco + m * 16 + chp * 4;
    float Sv[4], Tv[4];
#pragma unroll
    for (int r = 0; r < 4; ++r) { Sv[r] = Sc[cor0 + r]; Tv[r] = Tc[cor0 + r]; }
#pragma unroll
    for (int n = 0; n < 4; ++n) {
      const int s = s0 + wp + n * 16 + l15;
      if (s < SPAT) {
        float* op = out + ((size_t)b * COUT + cor0) * SPAT + s;
#pragma unroll
        for (int r = 0; r < 4; ++r) {
          float v = (float)acc[m][n][r] * Sv[r] + Tv[r];
          v = fminf(1.0f, fmaxf(-1.0f, v));
          op[(size_t)r * SPAT] = v;
        }
      }
    }
  }
}

extern "C" void kernel_launch(void* const* d_in, const int* in_sizes, int n_in,
                              void* d_out, int out_size, void* d_ws, size_t ws_size,
                              hipStream_t stream) {
  const float* x     = (const float*)d_in[0];
  const float* wgt   = (const float*)d_in[1];
  const float* gamma = (const float*)d_in[2];
  const float* beta  = (const float*)d_in[3];
  const float* rmean = (const float*)d_in[4];
  const float* rvar  = (const float*)d_in[5];
  float* out = (float*)d_out;

  int8_t* xp = (int8_t*)d_ws;
  const size_t xp_bytes = (size_t)BATCH * SPAD * CIN;        // 27.6 MB
  int8_t* wfrag = xp + xp_bytes;
  const size_t wfrag_bytes = (size_t)2 * 294912;             // 590 KB
  float* Sc = (float*)(wfrag + wfrag_bytes);
  float* Tc = Sc + COUT;

  pack_x_kernel<<<dim3(50, BATCH), 256, 0, stream>>>(x, xp);
  prep_w_kernel<<<COUT, 256, 0, stream>>>(wgt, gamma, beta, rmean, rvar, wfrag, Sc, Tc);
  conv_kernel<<<dim3(25, BATCH, 2), 256, 0, stream>>>(xp, wfrag, Sc, Tc, out);
}

// Round 11
// 101.252 us; speedup vs baseline: 1.1572x; 1.1572x over previous
//
#include <hip/hip_runtime.h>
#include <hip/hip_bf16.h>
#include <cstdint>
#include <cstddef>

// IR-Net binary conv 3x3 s1 p1 + BN(inference) + hardtanh, B=32 Cin=Cout=256 H=W=56.
// Ternary operands -> EXACT int8 MFMA implicit GEMM (mfma_i32_16x16x64_i8).
// R11 = R8 structure (unpinned af ping-pong, barrier-free taps, setprio) with
//   X LDS halved to ONE 32KB span buffer + single mid-kernel restage at s==9
//   (barrier/issueX/vmcnt0/barrier, once per block) -> 4-5 blocks/CU instead of
//   2; co-resident waves hide the af L2 latency that R8 exposed (R9/R10 proved
//   register-pinning can't fix it within the VGPR budget).

typedef int int4v __attribute__((ext_vector_type(4)));

#define CIN   256
#define COUT  256
#define SPAT  3136   // 56*56
#define SPAD  3364   // 58*58 padded spatial
#define BATCH 32
#define XHALF 32768  // 256 rows x 128 B

// ---------------- weight prep: standardize, sign, scatter to A-fragment order ----------------
__device__ inline float block_reduce(float v, float* red, int t) {
  red[t] = v; __syncthreads();
#pragma unroll
  for (int o = 128; o > 0; o >>= 1) {
    if (t < o) red[t] += red[t + o];
    __syncthreads();
  }
  float r = red[0];
  __syncthreads();
  return r;
}

__global__ __launch_bounds__(256) void prep_w_kernel(
    const float* __restrict__ wgt, const float* __restrict__ gamma,
    const float* __restrict__ beta, const float* __restrict__ rmean,
    const float* __restrict__ rvar, int8_t* __restrict__ wfrag,
    float* __restrict__ Sc, float* __restrict__ Tc) {
  const int co = blockIdx.x;
  const int t  = threadIdx.x;
  __shared__ float red[256];
  const float* wc = wgt + (size_t)co * 2304;
  float v[9];
#pragma unroll
  for (int j = 0; j < 9; ++j) v[j] = wc[t + j * 256];
  float s = 0.f;
#pragma unroll
  for (int j = 0; j < 9; ++j) s += v[j];
  const float total = block_reduce(s, red, t);
  const float mean = total * (1.0f / 2304.0f);
  float ss = 0.f, sa = 0.f;
#pragma unroll
  for (int j = 0; j < 9; ++j) {
    float d = v[j] - mean;
    ss += d * d;
    sa += fabsf(d);
  }
  const float var_sum = block_reduce(ss, red, t);
  const float abs_sum = block_reduce(sa, red, t);
  const float stdv = sqrtf(var_sum / 2303.0f);       // unbiased (ddof=1)
  const float mean_abs = abs_sum / (2304.0f * stdv); // mean |bw|
  const float sw = exp2f(rintf(log2f(mean_abs)));    // half-even like jnp.round

  const int z = co >> 7, row = co & 127;
  const int wv = row >> 6, m = (row >> 4) & 3, l15w = row & 15;
#pragma unroll
  for (int j = 0; j < 9; ++j) {
    int i = t + j * 256;          // i = cin*9 + tap  (OIHW flat)
    int cin = i / 9;
    int tap = i - cin * 9;
    float d = v[j] - mean;
    int8_t bits = (d > 0.f) ? (int8_t)1 : ((d < 0.f) ? (int8_t)-1 : (int8_t)0);
    // A-fragment order: [z][g=c0i*9+tap][wv][m*2+kb][lane(64)][e(16)]
    int c0i = cin >> 7, cl = cin & 127;
    int chunk = cl >> 4;                 // 0..7 (16 cin each)
    int kb = chunk >> 2, chp = chunk & 3, e = cl & 15;
    int lane = chp * 16 + l15w;
    int g = c0i * 9 + tap;
    size_t flat = (size_t)z * 294912 + (size_t)(g * 2 + wv) * 8192
                + (m * 2 + kb) * 1024 + lane * 16 + e;
    wfrag[flat] = bits;
  }
  if (t == 0) {
    float inv = gamma[co] / sqrtf(rvar[co] + 1e-5f);
    Sc[co] = sw * inv;
    Tc[co] = beta[co] - rmean[co] * inv;
  }
}

// ---------------- activation pack (+halo clear): sign(x) -> i8, padded [b][58*58][cin] ----------------
__global__ __launch_bounds__(256) void pack_x_kernel(const float* __restrict__ x,
                                                     int8_t* __restrict__ xp) {
  const int b   = blockIdx.y;
  const int tid = threadIdx.x;
  if (blockIdx.x == 49) {                // halo block: zero the 228 pad pixels
    int8_t* xpb = xp + (size_t)b * SPAD * CIN;
    const int4v z = (int4v){0, 0, 0, 0};
    for (int q = tid; q < 228 * 16; q += 256) {
      int p = q >> 4, c = q & 15;
      int pp;
      if (p < 58)       pp = p;                      // top row 0
      else if (p < 116) pp = 57 * 58 + (p - 58);     // bottom row 57
      else if (p < 172) pp = (p - 116 + 1) * 58;     // left col, rows 1..56
      else              pp = (p - 172 + 1) * 58 + 57;// right col, rows 1..56
      *(int4v*)(xpb + (size_t)pp * CIN + c * 16) = z;
    }
    return;
  }
  const int s0  = blockIdx.x * 64;
  __shared__ uint8_t xt[64][272];        // 64 px x 256 cin bytes (+16 pad)
  const int g  = tid >> 6;               // cin quarter 0..3
  const int si = tid & 63;               // px within chunk
#pragma unroll
  for (int k = 0; k < 4; ++k) {          // 16 cin per iter -> one 16B LDS store
    const int cin16 = (g * 4 + k) * 16;
    const float* src = x + ((size_t)b * CIN + cin16) * SPAT + s0 + si;
    uint32_t w[4] = {0u, 0u, 0u, 0u};
#pragma unroll
    for (int e = 0; e < 16; ++e) {
      float v = src[(size_t)e * SPAT];
      uint32_t sb = (v > 0.f) ? 1u : ((v < 0.f) ? 0xFFu : 0u);
      w[e >> 2] |= sb << ((e & 3) * 8);
    }
    *(int4v*)&xt[si][cin16] = (int4v){(int)w[0], (int)w[1], (int)w[2], (int)w[3]};
  }
  __syncthreads();
  const int row = tid >> 2;              // px 0..63
  const int sub = tid & 3;               // 64-cin quarter
  const int s = s0 + row;
  const int h = s / 56;
  int8_t* dst = xp + ((size_t)b * SPAD + (size_t)(s + 2 * h + 59)) * CIN + sub * 64;
#pragma unroll
  for (int j = 0; j < 4; ++j)
    *(int4v*)(dst + j * 16) = *(const int4v*)&xt[row][sub * 64 + j * 16];
}

// ---------------- async global->LDS, 16B ----------------
__device__ __forceinline__ void gload_lds16(const void* g, void* l) {
  __builtin_amdgcn_global_load_lds(
      (const __attribute__((address_space(1))) uint32_t*)g,
      (__attribute__((address_space(3))) uint32_t*)l, 16, 0, 0);
}

// ---------------- binary conv as implicit GEMM (i8 MFMA) ----------------
// Block: 128co x 128px, one image; 4 waves, wave = 64co x 64px, acc[4][4] i32.
// 18 steps (2 cin-halves x 9 taps), fully unrolled; X single 32KB span buffer
// restaged once at s==9. W: global->reg ping-pong (unpinned). 4-5 blocks/CU.
__global__ __launch_bounds__(256, 2) void conv_kernel(
    const int8_t* __restrict__ xp, const int8_t* __restrict__ wfrag,
    const float* __restrict__ Sc, const float* __restrict__ Tc,
    float* __restrict__ out) {
  const int tile = blockIdx.x;           // 0..24
  const int b    = blockIdx.y;           // 0..31
  const int z    = blockIdx.z;           // co half
  const int co0  = z * 128;
  const int s0   = tile * 128;

  const int tid  = threadIdx.x;
  const int lane = tid & 63;
  const int wave = tid >> 6;
  const int wv   = wave >> 1;            // co 64-half within block
  const int wco  = wv * 64;
  const int wp   = (wave & 1) * 64;      // px 64-half
  const int l15  = lane & 15;
  const int chp  = lane >> 4;            // 16B k-chunk position 0..3

  __shared__ uint8_t XsF[XHALF];         // 32 KB: one cin-half, 128B rows, swizzled

  const int h0   = s0 / 56;
  const int base = s0 + 2 * h0;          // padded(s)=s+2h+59; base = padded(s0)-59

  // per-lane row offsets rel. to base (r = offn + tapoff in [0,249])
  int offn[4];
#pragma unroll
  for (int n = 0; n < 4; ++n) {
    int s = s0 + wp + n * 16 + l15;
    int sc = s < SPAT ? s : SPAT - 1;    // dummy px clamped (stores masked)
    int h = sc / 56;
    offn[n] = sc + 2 * h + 59 - base;    // in [59, 190]
  }

  const int8_t* xb  = xp + (size_t)b * SPAD * CIN;
  const int8_t* wba = wfrag + (size_t)z * 294912 + (size_t)wv * 8192 + lane * 16;

  // stage one cin-half: 2048 16B chunks (256 rows x 8), source pre-swizzled
  auto issueX = [&](int c0e) {
#pragma unroll
    for (int j = 0; j < 8; ++j) {
      int q   = j * 256 + tid;
      int row = q >> 3, c = q & 7;
      int gr  = base + row;
      if (gr > SPAD - 1) gr = SPAD - 1;  // clamp: only feeds dummy px
      gload_lds16(xb + (size_t)gr * CIN + c0e + ((c ^ (row & 7)) << 4),
                  XsF + (q << 4));
    }
  };

  int4v af[2][8];                        // ping-pong prefetch (64 VGPR), unpinned
  auto loadAf = [&](int g, int buf) {
#pragma unroll
    for (int q8 = 0; q8 < 8; ++q8)
      af[buf][q8] = *(const int4v*)(wba + (size_t)g * 16384 + q8 * 1024);
  };

  int4v acc[4][4];
#pragma unroll
  for (int m = 0; m < 4; ++m)
#pragma unroll
    for (int n = 0; n < 4; ++n) acc[m][n] = (int4v){0, 0, 0, 0};

  // prologue: X half0 + af0; full drain once (robust vs issue reordering)
  issueX(0);
  loadAf(0, 0);
  asm volatile("s_waitcnt vmcnt(0)" ::: "memory");
  __builtin_amdgcn_s_barrier();          // all waves' X half0 visible

#pragma unroll
  for (int s = 0; s < 18; ++s) {
    const int cur = s & 1;
    const int tap = s < 9 ? s : s - 9;
    const int tapoff = (tap / 3) * 58 + (tap - (tap / 3) * 3) - 59;

    if (s == 9) {                        // restage X with cin 128..255
      asm volatile("s_waitcnt lgkmcnt(0)" ::: "memory");
      __builtin_amdgcn_s_barrier();      // everyone done reading half0
      issueX(128);
      asm volatile("s_waitcnt vmcnt(0)" ::: "memory");  // own DMA (+af) retired
      __builtin_amdgcn_s_barrier();      // all DMA landed
    }

    // bf reads: XOR-swizzled chunk within 128B row
    int4v bf[8];
#pragma unroll
    for (int kb = 0; kb < 2; ++kb)
#pragma unroll
      for (int n = 0; n < 4; ++n) {
        int r = offn[n] + tapoff;
        bf[kb * 4 + n] = *(const int4v*)(XsF + (r << 7)
                                         + (((kb * 4 + chp) ^ (r & 7)) << 4));
      }

    if (s < 17) loadAf(s + 1, cur ^ 1);  // unpinned; TLP hides the latency

    __builtin_amdgcn_s_setprio(1);
#pragma unroll
    for (int kb = 0; kb < 2; ++kb)
#pragma unroll
      for (int m = 0; m < 4; ++m)
#pragma unroll
        for (int n = 0; n < 4; ++n)
          acc[m][n] = __builtin_amdgcn_mfma_i32_16x16x64_i8(
              af[cur][m * 2 + kb], bf[kb * 4 + n], acc[m][n], 0, 0, 0);
    __builtin_amdgcn_s_setprio(0);
  }

  // epilogue: out = clip((float)acc * S + T), layout [b][co][s]
#pragma unroll
  for (int m = 0; m < 4; ++m) {
    const int cor0 = co0 + wco + m * 16 + chp * 4;
    float Sv[4], Tv[4];
#pragma unroll
    for (int r = 0; r < 4; ++r) { Sv[r] = Sc[cor0 + r]; Tv[r] = Tc[cor0 + r]; }
#pragma unroll
    for (int n = 0; n < 4; ++n) {
      const int s = s0 + wp + n * 16 + l15;
      if (s < SPAT) {
        float* op = out + ((size_t)b * COUT + cor0) * SPAT + s;
#pragma unroll
        for (int r = 0; r < 4; ++r) {
          float v = (float)acc[m][n][r] * Sv[r] + Tv[r];
          v = fminf(1.0f, fmaxf(-1.0f, v));
          op[(size_t)r * SPAT] = v;
        }
      }
    }
  }
}

extern "C" void kernel_launch(void* const* d_in, const int* in_sizes, int n_in,
                              void* d_out, int out_size, void* d_ws, size_t ws_size,
                              hipStream_t stream) {
  const float* x     = (const float*)d_in[0];
  const float* wgt   = (const float*)d_in[1];
  const float* gamma = (const float*)d_in[2];
  const float* beta  = (const float*)d_in[3];
  const float* rmean = (const float*)d_in[4];
  const float* rvar  = (const float*)d_in[5];
  float* out = (float*)d_out;

  int8_t* xp = (int8_t*)d_ws;
  const size_t xp_bytes = (size_t)BATCH * SPAD * CIN;        // 27.6 MB
  int8_t* wfrag = xp + xp_bytes;
  const size_t wfrag_bytes = (size_t)2 * 294912;             // 590 KB
  float* Sc = (float*)(wfrag + wfrag_bytes);
  float* Tc = Sc + COUT;

  pack_x_kernel<<<dim3(50, BATCH), 256, 0, stream>>>(x, xp);
  prep_w_kernel<<<COUT, 256, 0, stream>>>(wgt, gamma, beta, rmean, rvar, wfrag, Sc, Tc);
  conv_kernel<<<dim3(25, BATCH, 2), 256, 0, stream>>>(xp, wfrag, Sc, Tc, out);
}